// Round 1
// baseline (843.902 us; speedup 1.0000x reference)
//
#include <hip/hip_runtime.h>
#include <math.h>

// Tril2Diff: out[b] = L @ L^T where L is 128x128 lower-triangular scattered
// from x[b] (8256 tril values), diagonal replaced by log1p(exp(d)+1e-12).
//
// Strategy: memory-bound problem (~807 MB traffic -> ~128us floor).
// fp32 VALU matmul would be ~220us (no fp32 MFMA on CDNA4), so cast L to
// bf16 in LDS and use mfma_f32_32x32x16_bf16 (fp32 accumulate). Error
// ~0.4% relative << 4.1 absmax threshold.

#define DIM       128
#define NTRIL     8256          // 128*129/2
#define LDS_STRIDE 136          // bf16 per row: 128 + 8 pad -> 272 B = 17 quads (kills 32-way conflicts)
#define ROW_BYTES 272

typedef __bf16 bf16x8 __attribute__((ext_vector_type(8)));
typedef float  f32x16 __attribute__((ext_vector_type(16)));

__global__ __launch_bounds__(256) void tril2diff_kernel(
    const float* __restrict__ x, float* __restrict__ out)
{
    __shared__ alignas(16) __bf16 Lsh[DIM * LDS_STRIDE];

    const int b   = blockIdx.x;
    const int tid = threadIdx.x;

    // ---- phase 0: zero LDS (upper triangle + pad must be 0 for full-K MFMA) ----
    // 128*136 bf16 = 8704 dwords = 34 * 256 exactly
    unsigned int* lz = (unsigned int*)Lsh;
    #pragma unroll
    for (int i = 0; i < 34; ++i)
        lz[tid + i * 256] = 0u;
    __syncthreads();

    // ---- phase 1: scatter x -> L (bf16), softplus diagonal ----
    const float* xb = x + (size_t)b * NTRIL;
    for (int i = 0; i < 33; ++i) {
        int t = tid + i * 256;
        if (t < NTRIL) {
            float v = xb[t];                       // coalesced: consecutive tid -> consecutive t
            // flat tril index -> row r: r = floor((sqrt(8t+1)-1)/2), with integer fixup
            int r = (int)((sqrtf(8.0f * (float)t + 1.0f) - 1.0f) * 0.5f);
            while ((r + 1) * (r + 2) / 2 <= t) ++r;
            while (r * (r + 1) / 2 > t) --r;
            int c = t - r * (r + 1) / 2;
            if (c == r) v = log1pf(expf(v) + 1e-12f);   // softplus-like, matches ref
            Lsh[r * LDS_STRIDE + c] = (__bf16)v;
        }
    }
    __syncthreads();

    // ---- phase 2: C = L * L^T via 32x32x16 bf16 MFMA ----
    // 4 waves; wave w owns the 64x64 quadrant (w>>1, w&1), as 2x2 tiles of 32x32.
    // A-frag rows = i-block rows of L; B-frag (B = L^T) rows = j-block rows of L:
    // identical LDS load pattern for both (8 contiguous bf16 per lane, b128).
    const int lane = tid & 63;
    const int wv   = tid >> 6;
    const int i0   = (wv >> 1) * 64;
    const int j0   = (wv & 1) * 64;
    const int cl   = lane & 31;      // row-within-32-block (A) / col (B) selector
    const int hh   = lane >> 5;      // k-half selector

    f32x16 acc00 = {0}, acc01 = {0}, acc10 = {0}, acc11 = {0};

    const char* lb = (const char*)Lsh;
    #pragma unroll
    for (int ks = 0; ks < 8; ++ks) {
        const int koff = ks * 32 + hh * 16;   // byte offset of this lane's 8-bf16 k-chunk
        bf16x8 a0 = *(const bf16x8*)(lb + (i0      + cl) * ROW_BYTES + koff);
        bf16x8 a1 = *(const bf16x8*)(lb + (i0 + 32 + cl) * ROW_BYTES + koff);
        bf16x8 b0 = *(const bf16x8*)(lb + (j0      + cl) * ROW_BYTES + koff);
        bf16x8 b1 = *(const bf16x8*)(lb + (j0 + 32 + cl) * ROW_BYTES + koff);
        acc00 = __builtin_amdgcn_mfma_f32_32x32x16_bf16(a0, b0, acc00, 0, 0, 0);
        acc01 = __builtin_amdgcn_mfma_f32_32x32x16_bf16(a0, b1, acc01, 0, 0, 0);
        acc10 = __builtin_amdgcn_mfma_f32_32x32x16_bf16(a1, b0, acc10, 0, 0, 0);
        acc11 = __builtin_amdgcn_mfma_f32_32x32x16_bf16(a1, b1, acc11, 0, 0, 0);
    }

    // ---- phase 3: store (C/D layout: col=lane&31, row=(reg&3)+8*(reg>>2)+4*(lane>>5)) ----
    // Each 32-lane half-wave writes 128 contiguous bytes per store -> coalesced.
    float* ob = out + (size_t)b * (DIM * DIM);
    #pragma unroll
    for (int reg = 0; reg < 16; ++reg) {
        const int row = (reg & 3) + 8 * (reg >> 2) + 4 * hh;
        ob[(i0      + row) * DIM + j0      + cl] = acc00[reg];
        ob[(i0      + row) * DIM + j0 + 32 + cl] = acc01[reg];
        ob[(i0 + 32 + row) * DIM + j0      + cl] = acc10[reg];
        ob[(i0 + 32 + row) * DIM + j0 + 32 + cl] = acc11[reg];
    }
}

extern "C" void kernel_launch(void* const* d_in, const int* in_sizes, int n_in,
                              void* d_out, int out_size, void* d_ws, size_t ws_size,
                              hipStream_t stream) {
    const float* x = (const float*)d_in[0];
    float* out = (float*)d_out;
    const int batch = in_sizes[0] / NTRIL;   // 8192
    tril2diff_kernel<<<batch, 256, 0, stream>>>(x, out);
}